// Round 12
// baseline (377.130 us; speedup 1.0000x reference)
//
#include <hip/hip_runtime.h>
#include <hip/hip_bf16.h>

typedef __bf16 bf16x8 __attribute__((ext_vector_type(8)));
typedef float f32x4 __attribute__((ext_vector_type(4)));

#define ATT_SCALE 0.125f   // 1/sqrt(64)

static __device__ __forceinline__ unsigned short f2bf(float f){
  unsigned u = __float_as_uint(f);
  u += 0x7fffu + ((u >> 16) & 1u);          // RNE
  return (unsigned short)(u >> 16);
}
static __device__ __forceinline__ bf16x8 ld_bf8(const unsigned short* p){
  uint4 u = *(const uint4*)p;
  return __builtin_bit_cast(bf16x8, u);
}
static __device__ __forceinline__ f32x4 mfma16(bf16x8 a, bf16x8 b, f32x4 c){
  return __builtin_amdgcn_mfma_f32_16x16x32_bf16(a, b, c, 0, 0, 0);
}
static __device__ __forceinline__ void gload16(const unsigned short* g, unsigned short* l){
  __builtin_amdgcn_global_load_lds(
      (const __attribute__((address_space(1))) unsigned*)g,
      (__attribute__((address_space(3))) unsigned*)l, 16, 0, 0);
}
// LDS-only barrier: does NOT drain vmcnt -> global stores/loads stay in flight
static __device__ __forceinline__ void lgkm_bar(){
  asm volatile("s_waitcnt lgkmcnt(0)" ::: "memory");
  __builtin_amdgcn_s_barrier();
  __builtin_amdgcn_sched_barrier(0);
}

// ---------------- cast fp32 -> bf16, 3 modalities in one launch ----------------
struct CastArgs { const float* src[3]; unsigned short* dst[3]; };
__global__ __launch_bounds__(256) void cast_f32_bf16(CastArgs a){
  const float* in = a.src[blockIdx.y];
  unsigned short* out = a.dst[blockIdx.y];
  int i = blockIdx.x*256 + threadIdx.x;
  float4 f = ((const float4*)in)[i];
  ushort4 o = {f2bf(f.x), f2bf(f.y), f2bf(f.z), f2bf(f.w)};
  ((ushort4*)out)[i] = o;
}

// ---------------- weight transpose+cast: W[1024][N] fp32 -> WT[N][1024] bf16 ----------------
struct WtArgs { const float* src[9]; unsigned short* dst[9]; int N[9]; };
__global__ void wtrans(WtArgs a){
  int z = blockIdx.z;
  int N = a.N[z];
  int n0 = blockIdx.x*32;
  if(n0 >= N) return;
  int k0 = blockIdx.y*32;
  const float* W = a.src[z];
  unsigned short* WT = a.dst[z];
  __shared__ float t[32][33];
  int tx = threadIdx.x, ty = threadIdx.y;        // block (32,8)
  #pragma unroll
  for(int r=0;r<4;++r){
    int row = ty + r*8;
    t[row][tx] = W[(size_t)(k0+row)*N + n0+tx];
  }
  __syncthreads();
  #pragma unroll
  for(int r=0;r<4;++r){
    int row = ty + r*8;
    WT[(size_t)(n0+row)*1024 + k0+tx] = f2bf(t[tx][row]);
  }
}

// ---------------- fused QKV GEMM: C[4096][2048] = X[4096][1024] @ WT[2048][1024]^T ----------------
struct GemmArgs {
  const unsigned short* X[3]; const unsigned short* WT[3];
  const float* bq[3]; const float* bk[3]; const float* bv[3];
  unsigned short* C[3];
};
__global__ __launch_bounds__(256) void gemm_qkv(GemmArgs g){
  __shared__ unsigned short As[128*32];
  __shared__ unsigned short Bs[128*32];
  int z = blockIdx.z;
  const unsigned short* A  = g.X[z];
  const unsigned short* Bt = g.WT[z];
  unsigned short* C = g.C[z];
  int tid = threadIdx.x;
  int wave = tid>>6, lane = tid&63, l15 = lane&15, l4 = lane>>4;
  int m0 = blockIdx.y*128, n0 = blockIdx.x*128;
  int wr = wave>>1, wc = wave&1;
  f32x4 acc[4][4];
  #pragma unroll
  for(int i=0;i<4;++i)
    #pragma unroll
    for(int j=0;j<4;++j) acc[i][j] = (f32x4){0.f,0.f,0.f,0.f};

  int c0r = tid,      row0 = c0r>>2, col0 = (c0r&3)*8;
  int c1r = tid+256,  row1 = c1r>>2, col1 = (c1r&3)*8;
  const unsigned short* a0p = A  + (size_t)(m0+row0)*1024 + col0;
  const unsigned short* a1p = A  + (size_t)(m0+row1)*1024 + col1;
  const unsigned short* b0p = Bt + (size_t)(n0+row0)*1024 + col0;
  const unsigned short* b1p = Bt + (size_t)(n0+row1)*1024 + col1;

  for(int k0=0; k0<1024; k0+=32){
    gload16(a0p + k0, &As[c0r*8]);
    gload16(a1p + k0, &As[c1r*8]);
    gload16(b0p + k0, &Bs[c0r*8]);
    gload16(b1p + k0, &Bs[c1r*8]);
    __syncthreads();
    bf16x8 af[4], bfr[4];
    #pragma unroll
    for(int t=0;t<4;++t){
      af[t]  = ld_bf8(&As[(wr*64 + t*16 + l15)*32 + 8*l4]);
      bfr[t] = ld_bf8(&Bs[(wc*64 + t*16 + l15)*32 + 8*l4]);
    }
    #pragma unroll
    for(int mt=0;mt<4;++mt)
      #pragma unroll
      for(int nt=0;nt<4;++nt)
        acc[mt][nt] = mfma16(af[mt], bfr[nt], acc[mt][nt]);
    __syncthreads();
  }

  #pragma unroll
  for(int mt=0;mt<4;++mt){
    #pragma unroll
    for(int nt=0;nt<4;++nt){
      int col = n0 + wc*64 + nt*16 + l15;
      float bb;
      if(col < 1024)      bb = g.bq[z][col];
      else if(col < 1536) bb = g.bk[z][col-1024];
      else                bb = g.bv[z][col-1536];
      #pragma unroll
      for(int r=0;r<4;++r){
        int row = m0 + wr*64 + mt*16 + l4*4 + r;
        C[(size_t)row*2048 + col] = f2bf(acc[mt][nt][r] + bb);
      }
    }
  }
}

// ---------------- V transpose: V[4096][512] (stride 2048) -> VT[512][4096] ----------------
struct VtArgs { const unsigned short* in[3]; unsigned short* out[3]; };
__global__ __launch_bounds__(256) void vtrans(VtArgs a){
  int z = blockIdx.z;
  const unsigned short* in = a.in[z];
  unsigned short* out = a.out[z];
  __shared__ unsigned short T[64][72];
  int r0 = blockIdx.x*64, c0 = blockIdx.y*64;
  int tid = threadIdx.x;
  #pragma unroll
  for(int p=0;p<4;++p){
    int e = p*1024 + tid*4;
    int row = e>>6, col = e&63;
    *(ushort4*)&T[row][col] = *(const ushort4*)&in[(size_t)(r0+row)*2048 + c0+col];
  }
  __syncthreads();
  #pragma unroll
  for(int p=0;p<4;++p){
    int e = p*1024 + tid*4;
    int orow = e>>6, ocol = e&63;
    ushort4 v = {T[ocol][orow], T[ocol+1][orow], T[ocol+2][orow], T[ocol+3][orow]};
    *(ushort4*)&out[(size_t)(c0+orow)*4096 + r0+ocol] = v;
  }
}

// ---------------- fused attention: 3 branches, one launch ----------------
// 12288 blocks x 256 threads (4 waves), 16.5 KB LDS.
// Swapped QK^T (mfma(K,Q)): lane holds S[q=l15][k=wave*128+t*16+l4*4+r] in 32 regs.
// Softmax fully in-register: lane-local over 32 + 2 shfl + cross-wave LDS combine.
// P -> LDS as bf16 only (16 KB), 4-bit XOR swizzle: unit16' = unit16 ^ l15 (row).
// probs fp32 stored from s[] AFTER PV (no load follows any store).
struct AttnArgs {
  const unsigned short* Q[3];  const unsigned short* Ka[3]; const unsigned short* Kb[3];
  const unsigned short* VTa[3]; const unsigned short* VTb[3];
  const float* mA[3]; const float* mB[3];
  float* ctx[3]; float* probs[3];
};
__global__ __launch_bounds__(256) void attn(AttnArgs A){
  __shared__ unsigned short Pl[16*512];       // 16 KB bf16 P
  __shared__ float2 red[4][16];               // per-wave (m,sum) per q-row
  int wg = blockIdx.x;
  int id = (wg & 7)*1536 + (wg >> 3);         // bijective (12288 % 8 == 0)
  int br = id >> 12;
  int rem = id & 4095;
  int bh = rem >> 5, qt = rem & 31;
  int b = bh >> 4, h = bh & 15;
  const unsigned short* Q   = A.Q[br];
  const unsigned short* Ka  = A.Ka[br];
  const unsigned short* Kb  = A.Kb[br];
  const unsigned short* VTa = A.VTa[br];
  const unsigned short* VTb = A.VTb[br];
  const float* mA = A.mA[br];
  const float* mB = A.mB[br];
  float* ctx   = A.ctx[br];
  float* probs = A.probs[br];

  int tid = threadIdx.x, wave = tid>>6, lane = tid&63, l15 = lane&15, l4 = lane>>4;
  int q0 = qt*16;
  int kb0 = wave*128;

  // ---- Q fragments ----
  const unsigned short* qp = Q + (size_t)(b*512 + q0 + l15)*2048 + h*64 + 8*l4;
  bf16x8 a0 = ld_bf8(qp);
  bf16x8 a1 = ld_bf8(qp + 32);

  const unsigned short* kap = Ka + (size_t)(b*512 + kb0 + l15)*2048 + h*32 + 8*l4;
  const unsigned short* kbp = Kb + (size_t)(b*512 + kb0 + l15)*2048 + h*32 + 8*l4;

  // ---- V prefetch (4 fragments; rest loaded lazily in PV) ----
  int d0 = wave*16 + l15;
  const unsigned short* vb0 = (d0<32 ? VTa + (size_t)(h*32+d0)*4096 : VTb + (size_t)(h*32+d0-32)*4096) + b*512;
  bf16x8 vpre[4];
  #pragma unroll
  for(int kc=0;kc<4;++kc) vpre[kc] = ld_bf8(vb0 + kc*32 + 8*l4);

  // ---- swapped QK^T in two 4-batches (caps K-register peak at 32) ----
  f32x4 s[8];
  {
    bf16x8 k0[4], k1[4];
    #pragma unroll
    for(int t=0;t<4;++t){
      k0[t] = ld_bf8(kap + (size_t)t*16*2048);
      k1[t] = ld_bf8(kbp + (size_t)t*16*2048);
    }
    #pragma unroll
    for(int t=0;t<4;++t){
      f32x4 acc = (f32x4){0.f,0.f,0.f,0.f};
      acc = mfma16(k0[t], a0, acc);
      acc = mfma16(k1[t], a1, acc);
      s[t] = acc;
    }
  }
  {
    bf16x8 k0[4], k1[4];
    #pragma unroll
    for(int t=0;t<4;++t){
      k0[t] = ld_bf8(kap + (size_t)(t+4)*16*2048);
      k1[t] = ld_bf8(kbp + (size_t)(t+4)*16*2048);
    }
    #pragma unroll
    for(int t=0;t<4;++t){
      f32x4 acc = (f32x4){0.f,0.f,0.f,0.f};
      acc = mfma16(k0[t], a0, acc);
      acc = mfma16(k1[t], a1, acc);
      s[t+4] = acc;
    }
  }

  // ---- masks (lazy: L2-hot 2KB rows), scale, lane-local softmax ----
  float m = -1e30f;
  #pragma unroll
  for(int t=0;t<8;++t){
    f32x4 v = (f32x4){0.f,0.f,0.f,0.f};
    int c = b*512 + kb0 + t*16 + l4*4;
    if(mA) v += *(const f32x4*)&mA[c];
    if(mB) v += *(const f32x4*)&mB[c];
    s[t] = s[t]*ATT_SCALE + v;
    m = fmaxf(m, fmaxf(fmaxf(s[t][0], s[t][1]), fmaxf(s[t][2], s[t][3])));
  }
  m = fmaxf(m, __shfl_xor(m, 16));
  m = fmaxf(m, __shfl_xor(m, 32));
  float sum = 0.f;
  #pragma unroll
  for(int t=0;t<8;++t){
    #pragma unroll
    for(int r=0;r<4;++r){
      s[t][r] = __expf(s[t][r] - m);
      sum += s[t][r];
    }
  }
  sum += __shfl_xor(sum, 16);
  sum += __shfl_xor(sum, 32);
  if(l4 == 0) red[wave][l15] = make_float2(m, sum);
  lgkm_bar();

  float2 pr0 = red[0][l15], pr1 = red[1][l15], pr2 = red[2][l15], pr3 = red[3][l15];
  float M = fmaxf(fmaxf(pr0.x, pr1.x), fmaxf(pr2.x, pr3.x));
  float T = pr0.y*__expf(pr0.x - M) + pr1.y*__expf(pr1.x - M)
          + pr2.y*__expf(pr2.x - M) + pr3.y*__expf(pr3.x - M);
  float scale = __expf(m - M) / T;

  #pragma unroll
  for(int t=0;t<8;++t) s[t] = s[t]*scale;

  // ---- bf16 P -> LDS, 4-bit swizzle (PV reads land at b128 4-way minimum) ----
  #pragma unroll
  for(int t=0;t<8;++t){
    int u16 = wave*16 + t*2 + (l4>>1);
    ushort4 pb = {f2bf(s[t][0]), f2bf(s[t][1]), f2bf(s[t][2]), f2bf(s[t][3])};
    *(ushort4*)&Pl[l15*512 + ((u16 ^ l15) << 3) + (l4&1)*4] = pb;
  }
  lgkm_bar();

  // ---- PV: wave = one 16-col d-tile; bf16 ds_read_b128 A-fragments ----
  const unsigned short* prow = Pl + l15*512;
  f32x4 accE = (f32x4){0.f,0.f,0.f,0.f}, accO = (f32x4){0.f,0.f,0.f,0.f};
  #pragma unroll
  for(int kc=0;kc<16;++kc){
    int u = kc*4 + l4;
    bf16x8 a = ld_bf8(prow + ((u ^ l15) << 3));
    bf16x8 bb = (kc < 4) ? vpre[kc] : ld_bf8(vb0 + kc*32 + 8*l4);
    if(kc & 1) accO = mfma16(a, bb, accO);
    else       accE = mfma16(a, bb, accE);
  }
  f32x4 acc = accE + accO;
  #pragma unroll
  for(int r=0;r<4;++r){
    int row = q0 + l4*4 + r;
    ctx[((size_t)(b*512+row))*1024 + h*64 + d0] = acc[r];
  }

  // ---- deferred probs store (drains at endpgm; nothing waits on it) ----
  __builtin_amdgcn_sched_barrier(0);
  float* po = probs + ((size_t)bh*512 + q0 + l15)*512 + kb0 + l4*4;
  #pragma unroll
  for(int t=0;t<8;++t)
    *(f32x4*)&po[t*16] = s[t];
}

// ---------------- launch ----------------
extern "C" void kernel_launch(void* const* d_in, const int* in_sizes, int n_in,
                              void* d_out, int out_size, void* d_ws, size_t ws_size,
                              hipStream_t stream){
  const float* x[3]    = {(const float*)d_in[0], (const float*)d_in[2], (const float*)d_in[4]};
  const float* mask[3] = {(const float*)d_in[1], (const float*)d_in[3], (const float*)d_in[5]};
  const float *wq[3], *bq[3], *wk[3], *bk[3], *wv[3], *bv[3];
  for(int i=0;i<3;++i){
    wq[i]=(const float*)d_in[6+6*i];  bq[i]=(const float*)d_in[7+6*i];
    wk[i]=(const float*)d_in[8+6*i];  bk[i]=(const float*)d_in[9+6*i];
    wv[i]=(const float*)d_in[10+6*i]; bv[i]=(const float*)d_in[11+6*i];
  }

  unsigned short* ws = (unsigned short*)d_ws;
  unsigned short *Xb[3], *WT[3], *QKV[3], *VT[3];
  for(int i=0;i<3;++i){
    Xb[i]  = ws + (size_t)i*4194304;            // 4096x1024 bf16 (dead after gemm)
    VT[i]  = Xb[i];                             // 512x4096 bf16, aliases Xb
    WT[i]  = ws + 12582912 + (size_t)i*2097152; // 2048x1024 bf16 packed [Wq;Wk;Wv]^T
    QKV[i] = ws + 18874368 + (size_t)i*8388608; // 4096x2048 bf16
  }

  CastArgs ca;
  for(int i=0;i<3;++i){ ca.src[i]=x[i]; ca.dst[i]=Xb[i]; }
  cast_f32_bf16<<<dim3(4096,3), 256, 0, stream>>>(ca);

  WtArgs wa;
  for(int i=0;i<3;++i){
    wa.src[3*i+0]=wq[i]; wa.dst[3*i+0]=WT[i];           wa.N[3*i+0]=1024;
    wa.src[3*i+1]=wk[i]; wa.dst[3*i+1]=WT[i]+1048576;   wa.N[3*i+1]=512;
    wa.src[3*i+2]=wv[i]; wa.dst[3*i+2]=WT[i]+1572864;   wa.N[3*i+2]=512;
  }
  wtrans<<<dim3(32,32,9), dim3(32,8), 0, stream>>>(wa);

  GemmArgs ga;
  for(int i=0;i<3;++i){
    ga.X[i]=Xb[i]; ga.WT[i]=WT[i]; ga.bq[i]=bq[i]; ga.bk[i]=bk[i]; ga.bv[i]=bv[i]; ga.C[i]=QKV[i];
  }
  gemm_qkv<<<dim3(16,32,3), 256, 0, stream>>>(ga);

  VtArgs va;
  for(int i=0;i<3;++i){ va.in[i]=QKV[i]+1536; va.out[i]=VT[i]; }
  vtrans<<<dim3(64,8,3), 256, 0, stream>>>(va);

  float* out = (float*)d_out;
  float* ctx2 = out;
  float* ctx1 = out + 4194304;
  float* ctx3 = out + 8388608;
  float* p2   = out + 12582912;
  float* p1   = out + 46137344;
  float* p3   = out + 79691776;

  AttnArgs aa;
  // br0 = "c2": q1, KV 2+3, no mask
  aa.Q[0]=QKV[0]; aa.Ka[0]=QKV[1]+1024; aa.Kb[0]=QKV[2]+1024; aa.VTa[0]=VT[1]; aa.VTb[0]=VT[2];
  aa.mA[0]=nullptr; aa.mB[0]=nullptr; aa.ctx[0]=ctx2; aa.probs[0]=p2;
  // br1 = "c1": q2, KV 1+3, mask1+mask3
  aa.Q[1]=QKV[1]; aa.Ka[1]=QKV[0]+1024; aa.Kb[1]=QKV[2]+1024; aa.VTa[1]=VT[0]; aa.VTb[1]=VT[2];
  aa.mA[1]=mask[0]; aa.mB[1]=mask[2]; aa.ctx[1]=ctx1; aa.probs[1]=p1;
  // br2 = "c3": q3, KV 1+2, mask1+mask2
  aa.Q[2]=QKV[2]; aa.Ka[2]=QKV[0]+1024; aa.Kb[2]=QKV[1]+1024; aa.VTa[2]=VT[0]; aa.VTb[2]=VT[1];
  aa.mA[2]=mask[0]; aa.mB[2]=mask[1]; aa.ctx[2]=ctx3; aa.probs[2]=p3;
  attn<<<12288, 256, 0, stream>>>(aa);
}

// Round 13
// 328.840 us; speedup vs baseline: 1.1469x; 1.1469x over previous
//
#include <hip/hip_runtime.h>
#include <hip/hip_bf16.h>

typedef __bf16 bf16x8 __attribute__((ext_vector_type(8)));
typedef float f32x4 __attribute__((ext_vector_type(4)));

#define ATT_SCALE 0.125f   // 1/sqrt(64)

static __device__ __forceinline__ unsigned short f2bf(float f){
  unsigned u = __float_as_uint(f);
  u += 0x7fffu + ((u >> 16) & 1u);          // RNE
  return (unsigned short)(u >> 16);
}
static __device__ __forceinline__ bf16x8 ld_bf8(const unsigned short* p){
  uint4 u = *(const uint4*)p;
  return __builtin_bit_cast(bf16x8, u);
}
static __device__ __forceinline__ f32x4 mfma16(bf16x8 a, bf16x8 b, f32x4 c){
  return __builtin_amdgcn_mfma_f32_16x16x32_bf16(a, b, c, 0, 0, 0);
}
static __device__ __forceinline__ void gload16(const unsigned short* g, unsigned short* l){
  __builtin_amdgcn_global_load_lds(
      (const __attribute__((address_space(1))) unsigned*)g,
      (__attribute__((address_space(3))) unsigned*)l, 16, 0, 0);
}

// ---------------- cast fp32 -> bf16, 3 modalities in one launch ----------------
struct CastArgs { const float* src[3]; unsigned short* dst[3]; };
__global__ __launch_bounds__(256) void cast_f32_bf16(CastArgs a){
  const float* in = a.src[blockIdx.y];
  unsigned short* out = a.dst[blockIdx.y];
  int i = blockIdx.x*256 + threadIdx.x;
  float4 f = ((const float4*)in)[i];
  ushort4 o = {f2bf(f.x), f2bf(f.y), f2bf(f.z), f2bf(f.w)};
  ((ushort4*)out)[i] = o;
}

// ---------------- weight transpose+cast: W[1024][N] fp32 -> WT[N][1024] bf16 ----------------
struct WtArgs { const float* src[9]; unsigned short* dst[9]; int N[9]; };
__global__ void wtrans(WtArgs a){
  int z = blockIdx.z;
  int N = a.N[z];
  int n0 = blockIdx.x*32;
  if(n0 >= N) return;
  int k0 = blockIdx.y*32;
  const float* W = a.src[z];
  unsigned short* WT = a.dst[z];
  __shared__ float t[32][33];
  int tx = threadIdx.x, ty = threadIdx.y;        // block (32,8)
  #pragma unroll
  for(int r=0;r<4;++r){
    int row = ty + r*8;
    t[row][tx] = W[(size_t)(k0+row)*N + n0+tx];
  }
  __syncthreads();
  #pragma unroll
  for(int r=0;r<4;++r){
    int row = ty + r*8;
    WT[(size_t)(n0+row)*1024 + k0+tx] = f2bf(t[tx][row]);
  }
}

// ---------------- fused QKV GEMM: C[4096][2048] = X[4096][1024] @ WT[2048][1024]^T ----------------
struct GemmArgs {
  const unsigned short* X[3]; const unsigned short* WT[3];
  const float* bq[3]; const float* bk[3]; const float* bv[3];
  unsigned short* C[3];
};
__global__ __launch_bounds__(256) void gemm_qkv(GemmArgs g){
  __shared__ unsigned short As[128*32];
  __shared__ unsigned short Bs[128*32];
  int z = blockIdx.z;
  const unsigned short* A  = g.X[z];
  const unsigned short* Bt = g.WT[z];
  unsigned short* C = g.C[z];
  int tid = threadIdx.x;
  int wave = tid>>6, lane = tid&63, l15 = lane&15, l4 = lane>>4;
  int m0 = blockIdx.y*128, n0 = blockIdx.x*128;
  int wr = wave>>1, wc = wave&1;
  f32x4 acc[4][4];
  #pragma unroll
  for(int i=0;i<4;++i)
    #pragma unroll
    for(int j=0;j<4;++j) acc[i][j] = (f32x4){0.f,0.f,0.f,0.f};

  int c0r = tid,      row0 = c0r>>2, col0 = (c0r&3)*8;
  int c1r = tid+256,  row1 = c1r>>2, col1 = (c1r&3)*8;
  const unsigned short* a0p = A  + (size_t)(m0+row0)*1024 + col0;
  const unsigned short* a1p = A  + (size_t)(m0+row1)*1024 + col1;
  const unsigned short* b0p = Bt + (size_t)(n0+row0)*1024 + col0;
  const unsigned short* b1p = Bt + (size_t)(n0+row1)*1024 + col1;

  for(int k0=0; k0<1024; k0+=32){
    gload16(a0p + k0, &As[c0r*8]);
    gload16(a1p + k0, &As[c1r*8]);
    gload16(b0p + k0, &Bs[c0r*8]);
    gload16(b1p + k0, &Bs[c1r*8]);
    __syncthreads();
    bf16x8 af[4], bfr[4];
    #pragma unroll
    for(int t=0;t<4;++t){
      af[t]  = ld_bf8(&As[(wr*64 + t*16 + l15)*32 + 8*l4]);
      bfr[t] = ld_bf8(&Bs[(wc*64 + t*16 + l15)*32 + 8*l4]);
    }
    #pragma unroll
    for(int mt=0;mt<4;++mt)
      #pragma unroll
      for(int nt=0;nt<4;++nt)
        acc[mt][nt] = mfma16(af[mt], bfr[nt], acc[mt][nt]);
    __syncthreads();
  }

  #pragma unroll
  for(int mt=0;mt<4;++mt){
    #pragma unroll
    for(int nt=0;nt<4;++nt){
      int col = n0 + wc*64 + nt*16 + l15;
      float bb;
      if(col < 1024)      bb = g.bq[z][col];
      else if(col < 1536) bb = g.bk[z][col-1024];
      else                bb = g.bv[z][col-1536];
      #pragma unroll
      for(int r=0;r<4;++r){
        int row = m0 + wr*64 + mt*16 + l4*4 + r;
        C[(size_t)row*2048 + col] = f2bf(acc[mt][nt][r] + bb);
      }
    }
  }
}

// ---------------- V transpose: V[4096][512] (stride 2048) -> VT[512][4096] ----------------
struct VtArgs { const unsigned short* in[3]; unsigned short* out[3]; };
__global__ __launch_bounds__(256) void vtrans(VtArgs a){
  int z = blockIdx.z;
  const unsigned short* in = a.in[z];
  unsigned short* out = a.out[z];
  __shared__ unsigned short T[64][72];
  int r0 = blockIdx.x*64, c0 = blockIdx.y*64;
  int tid = threadIdx.x;
  #pragma unroll
  for(int p=0;p<4;++p){
    int e = p*1024 + tid*4;
    int row = e>>6, col = e&63;
    *(ushort4*)&T[row][col] = *(const ushort4*)&in[(size_t)(r0+row)*2048 + c0+col];
  }
  __syncthreads();
  #pragma unroll
  for(int p=0;p<4;++p){
    int e = p*1024 + tid*4;
    int orow = e>>6, ocol = e&63;
    ushort4 v = {T[ocol][orow], T[ocol+1][orow], T[ocol+2][orow], T[ocol+3][orow]};
    *(ushort4*)&out[(size_t)(c0+orow)*4096 + r0+ocol] = v;
  }
}

// ---------------- fused attention: 3 branches, one launch ----------------
// 12288 blocks x 256 threads (4 waves), 32KB LDS
// NO XCD swizzle: consecutive blocks = consecutive q-tiles -> probs writes form
// an advancing sequential frontier (HBM write locality; reads are L3-hits anyway).
// S layout: XOR-swizzled fp32 [16][512]: phys = row*512 + (((col>>2)^(row&7))<<2 | (col&3))
struct AttnArgs {
  const unsigned short* Q[3];  const unsigned short* Ka[3]; const unsigned short* Kb[3];
  const unsigned short* VTa[3]; const unsigned short* VTb[3];
  const float* mA[3]; const float* mB[3];
  float* ctx[3]; float* probs[3];
};
__global__ __launch_bounds__(256) void attn(AttnArgs A){
  __shared__ float S[16*512];                 // 32 KB
  int id = blockIdx.x;                        // sequential mapping (no swizzle)
  int br = id >> 12;
  int rem = id & 4095;
  int bh = rem >> 5, qt = rem & 31;
  int b = bh >> 4, h = bh & 15;
  const unsigned short* Q   = A.Q[br];
  const unsigned short* Ka  = A.Ka[br];
  const unsigned short* Kb  = A.Kb[br];
  const unsigned short* VTa = A.VTa[br];
  const unsigned short* VTb = A.VTb[br];
  const float* mA = A.mA[br];
  const float* mB = A.mB[br];
  float* ctx   = A.ctx[br];
  float* probs = A.probs[br];

  int tid = threadIdx.x, wave = tid>>6, lane = tid&63, l15 = lane&15, l4 = lane>>4;
  int q0 = qt*16;

  // ---- masks first (latency hides under everything else); float4, summed ----
  f32x4 msk4[2] = {{0.f,0.f,0.f,0.f},{0.f,0.f,0.f,0.f}};
  #pragma unroll
  for(int it=0; it<2; ++it){
    int c = it*256 + lane*4;
    if(mA) msk4[it] += *(const f32x4*)&mA[b*512 + c];
    if(mB) msk4[it] += *(const f32x4*)&mB[b*512 + c];
  }

  // ---- QK^T: batch-load all 16 K fragments, then MFMA chain ----
  const unsigned short* qp = Q + (size_t)(b*512 + q0 + l15)*2048 + h*64 + 8*l4;
  bf16x8 a0 = ld_bf8(qp);
  bf16x8 a1 = ld_bf8(qp + 32);
  int ct0 = wave*8;
  const unsigned short* kap = Ka + (size_t)(b*512 + ct0*16 + l15)*2048 + h*32 + 8*l4;
  const unsigned short* kbp = Kb + (size_t)(b*512 + ct0*16 + l15)*2048 + h*32 + 8*l4;
  bf16x8 ka[8], kb[8];
  #pragma unroll
  for(int t=0;t<8;++t){
    ka[t] = ld_bf8(kap + (size_t)t*16*2048);
    kb[t] = ld_bf8(kbp + (size_t)t*16*2048);
  }

  // ---- V prefetch issued while QK^T computes (T14) ----
  int d0 = wave*16 + l15;
  const unsigned short* vb0 = (d0<32 ? VTa + (size_t)(h*32+d0)*4096 : VTb + (size_t)(h*32+d0-32)*4096) + b*512;
  bf16x8 vpre[8];
  #pragma unroll
  for(int kc=0;kc<8;++kc) vpre[kc] = ld_bf8(vb0 + kc*32 + 8*l4);

  #pragma unroll
  for(int t=0;t<8;++t){
    int ct = ct0 + t;
    f32x4 acc = (f32x4){0.f,0.f,0.f,0.f};
    acc = mfma16(a0, ka[t], acc);
    acc = mfma16(a1, kb[t], acc);
    #pragma unroll
    for(int r=0;r<4;++r){
      int row = l4*4 + r;
      int col = ct*16 + l15;
      S[row*512 + ((((col>>2) ^ (row&7)) << 2) | (col&3))] = acc[r];
    }
  }
  __syncthreads();

  // ---- softmax: wave handles 4 rows; float4 lane-owns-4-consecutive-cols ----
  for(int rr=0; rr<4; ++rr){
    int r = wave*4 + rr;
    float* rowp = &S[r*512];
    int x = r & 7;
    f32x4 v[2];
    float m = -1e30f;
    #pragma unroll
    for(int it=0; it<2; ++it){
      int c4 = it*64 + lane;
      v[it] = *(const f32x4*)&rowp[(c4 ^ x) << 2];
      v[it] = v[it]*ATT_SCALE + msk4[it];
      m = fmaxf(m, fmaxf(fmaxf(v[it][0], v[it][1]), fmaxf(v[it][2], v[it][3])));
    }
    #pragma unroll
    for(int o=32;o;o>>=1) m = fmaxf(m, __shfl_xor(m, o));
    float sum = 0.f;
    #pragma unroll
    for(int it=0; it<2; ++it){
      #pragma unroll
      for(int j=0;j<4;++j){
        v[it][j] = __expf(v[it][j]-m);
        sum += v[it][j];
      }
    }
    #pragma unroll
    for(int o=32;o;o>>=1) sum += __shfl_xor(sum, o);
    float inv = 1.0f/sum;
    float* po = probs + ((size_t)bh*512 + (q0+r))*512;
    #pragma unroll
    for(int it=0; it<2; ++it){
      int c4 = it*64 + lane;
      f32x4 p = v[it]*inv;
      *(f32x4*)&rowp[(c4 ^ x) << 2] = p;
      *(f32x4*)&po[it*256 + lane*4] = p;
    }
  }
  __syncthreads();

  // ---- PV: wave = one 16-col d-tile, 16 rows ----
  int px = l15 & 7;
  const float* prowp = &S[l15*512];
  f32x4 accE = (f32x4){0.f,0.f,0.f,0.f}, accO = (f32x4){0.f,0.f,0.f,0.f};
  #pragma unroll
  for(int kc=0;kc<16;++kc){
    int c4a = kc*8 + 2*l4;
    float4 v0 = *(const float4*)&prowp[(c4a ^ px) << 2];
    float4 v1 = *(const float4*)&prowp[((c4a+1) ^ px) << 2];
    bf16x8 a = { (__bf16)v0.x,(__bf16)v0.y,(__bf16)v0.z,(__bf16)v0.w,
                 (__bf16)v1.x,(__bf16)v1.y,(__bf16)v1.z,(__bf16)v1.w };
    bf16x8 bb = (kc < 8) ? vpre[kc] : ld_bf8(vb0 + kc*32 + 8*l4);
    if(kc & 1) accO = mfma16(a, bb, accO);
    else       accE = mfma16(a, bb, accE);
  }
  f32x4 acc = accE + accO;
  #pragma unroll
  for(int r=0;r<4;++r){
    int row = q0 + l4*4 + r;
    ctx[((size_t)(b*512+row))*1024 + h*64 + d0] = acc[r];
  }
}

// ---------------- launch ----------------
extern "C" void kernel_launch(void* const* d_in, const int* in_sizes, int n_in,
                              void* d_out, int out_size, void* d_ws, size_t ws_size,
                              hipStream_t stream){
  const float* x[3]    = {(const float*)d_in[0], (const float*)d_in[2], (const float*)d_in[4]};
  const float* mask[3] = {(const float*)d_in[1], (const float*)d_in[3], (const float*)d_in[5]};
  const float *wq[3], *bq[3], *wk[3], *bk[3], *wv[3], *bv[3];
  for(int i=0;i<3;++i){
    wq[i]=(const float*)d_in[6+6*i];  bq[i]=(const float*)d_in[7+6*i];
    wk[i]=(const float*)d_in[8+6*i];  bk[i]=(const float*)d_in[9+6*i];
    wv[i]=(const float*)d_in[10+6*i]; bv[i]=(const float*)d_in[11+6*i];
  }

  unsigned short* ws = (unsigned short*)d_ws;
  unsigned short *Xb[3], *WT[3], *QKV[3], *VT[3];
  for(int i=0;i<3;++i){
    Xb[i]  = ws + (size_t)i*4194304;            // 4096x1024 bf16 (dead after gemm)
    VT[i]  = Xb[i];                             // 512x4096 bf16, aliases Xb
    WT[i]  = ws + 12582912 + (size_t)i*2097152; // 2048x1024 bf16 packed [Wq;Wk;Wv]^T
    QKV[i] = ws + 18874368 + (size_t)i*8388608; // 4096x2048 bf16
  }

  CastArgs ca;
  for(int i=0;i<3;++i){ ca.src[i]=x[i]; ca.dst[i]=Xb[i]; }
  cast_f32_bf16<<<dim3(4096,3), 256, 0, stream>>>(ca);

  WtArgs wa;
  for(int i=0;i<3;++i){
    wa.src[3*i+0]=wq[i]; wa.dst[3*i+0]=WT[i];           wa.N[3*i+0]=1024;
    wa.src[3*i+1]=wk[i]; wa.dst[3*i+1]=WT[i]+1048576;   wa.N[3*i+1]=512;
    wa.src[3*i+2]=wv[i]; wa.dst[3*i+2]=WT[i]+1572864;   wa.N[3*i+2]=512;
  }
  wtrans<<<dim3(32,32,9), dim3(32,8), 0, stream>>>(wa);

  GemmArgs ga;
  for(int i=0;i<3;++i){
    ga.X[i]=Xb[i]; ga.WT[i]=WT[i]; ga.bq[i]=bq[i]; ga.bk[i]=bk[i]; ga.bv[i]=bv[i]; ga.C[i]=QKV[i];
  }
  gemm_qkv<<<dim3(16,32,3), 256, 0, stream>>>(ga);

  VtArgs va;
  for(int i=0;i<3;++i){ va.in[i]=QKV[i]+1536; va.out[i]=VT[i]; }
  vtrans<<<dim3(64,8,3), 256, 0, stream>>>(va);

  float* out = (float*)d_out;
  float* ctx2 = out;
  float* ctx1 = out + 4194304;
  float* ctx3 = out + 8388608;
  float* p2   = out + 12582912;
  float* p1   = out + 46137344;
  float* p3   = out + 79691776;

  AttnArgs aa;
  // br0 = "c2": q1, KV 2+3, no mask
  aa.Q[0]=QKV[0]; aa.Ka[0]=QKV[1]+1024; aa.Kb[0]=QKV[2]+1024; aa.VTa[0]=VT[1]; aa.VTb[0]=VT[2];
  aa.mA[0]=nullptr; aa.mB[0]=nullptr; aa.ctx[0]=ctx2; aa.probs[0]=p2;
  // br1 = "c1": q2, KV 1+3, mask1+mask3
  aa.Q[1]=QKV[1]; aa.Ka[1]=QKV[0]+1024; aa.Kb[1]=QKV[2]+1024; aa.VTa[1]=VT[0]; aa.VTb[1]=VT[2];
  aa.mA[1]=mask[0]; aa.mB[1]=mask[2]; aa.ctx[1]=ctx1; aa.probs[1]=p1;
  // br2 = "c3": q3, KV 1+2, mask1+mask2
  aa.Q[2]=QKV[2]; aa.Ka[2]=QKV[0]+1024; aa.Kb[2]=QKV[1]+1024; aa.VTa[2]=VT[0]; aa.VTb[2]=VT[1];
  aa.mA[2]=mask[0]; aa.mB[2]=mask[1]; aa.ctx[2]=ctx3; aa.probs[2]=p3;
  attn<<<12288, 256, 0, stream>>>(aa);
}

// Round 14
// 303.017 us; speedup vs baseline: 1.2446x; 1.0852x over previous
//
#include <hip/hip_runtime.h>
#include <hip/hip_bf16.h>

typedef __bf16 bf16x8 __attribute__((ext_vector_type(8)));
typedef float f32x4 __attribute__((ext_vector_type(4)));

#define ATT_SCALE 0.125f   // 1/sqrt(64)

static __device__ __forceinline__ unsigned short f2bf(float f){
  unsigned u = __float_as_uint(f);
  u += 0x7fffu + ((u >> 16) & 1u);          // RNE
  return (unsigned short)(u >> 16);
}
static __device__ __forceinline__ bf16x8 ld_bf8(const unsigned short* p){
  uint4 u = *(const uint4*)p;
  return __builtin_bit_cast(bf16x8, u);
}
static __device__ __forceinline__ f32x4 mfma16(bf16x8 a, bf16x8 b, f32x4 c){
  return __builtin_amdgcn_mfma_f32_16x16x32_bf16(a, b, c, 0, 0, 0);
}
static __device__ __forceinline__ void gload16(const unsigned short* g, unsigned short* l){
  __builtin_amdgcn_global_load_lds(
      (const __attribute__((address_space(1))) unsigned*)g,
      (__attribute__((address_space(3))) unsigned*)l, 16, 0, 0);
}

// ---------------- cast fp32 -> bf16, 3 modalities in one launch ----------------
struct CastArgs { const float* src[3]; unsigned short* dst[3]; };
__global__ __launch_bounds__(256) void cast_f32_bf16(CastArgs a){
  const float* in = a.src[blockIdx.y];
  unsigned short* out = a.dst[blockIdx.y];
  int i = blockIdx.x*256 + threadIdx.x;
  float4 f = ((const float4*)in)[i];
  ushort4 o = {f2bf(f.x), f2bf(f.y), f2bf(f.z), f2bf(f.w)};
  ((ushort4*)out)[i] = o;
}

// ---------------- weight transpose+cast: W[1024][N] fp32 -> WT[N][1024] bf16 ----------------
struct WtArgs { const float* src[9]; unsigned short* dst[9]; int N[9]; };
__global__ void wtrans(WtArgs a){
  int z = blockIdx.z;
  int N = a.N[z];
  int n0 = blockIdx.x*32;
  if(n0 >= N) return;
  int k0 = blockIdx.y*32;
  const float* W = a.src[z];
  unsigned short* WT = a.dst[z];
  __shared__ float t[32][33];
  int tx = threadIdx.x, ty = threadIdx.y;        // block (32,8)
  #pragma unroll
  for(int r=0;r<4;++r){
    int row = ty + r*8;
    t[row][tx] = W[(size_t)(k0+row)*N + n0+tx];
  }
  __syncthreads();
  #pragma unroll
  for(int r=0;r<4;++r){
    int row = ty + r*8;
    WT[(size_t)(n0+row)*1024 + k0+tx] = f2bf(t[tx][row]);
  }
}

// ---------------- fused QKV GEMM: C[4096][2048] = X[4096][1024] @ WT[2048][1024]^T ----------------
struct GemmArgs {
  const unsigned short* X[3]; const unsigned short* WT[3];
  const float* bq[3]; const float* bk[3]; const float* bv[3];
  unsigned short* C[3];
};
__global__ __launch_bounds__(256) void gemm_qkv(GemmArgs g){
  __shared__ unsigned short As[128*32];
  __shared__ unsigned short Bs[128*32];
  int z = blockIdx.z;
  const unsigned short* A  = g.X[z];
  const unsigned short* Bt = g.WT[z];
  unsigned short* C = g.C[z];
  int tid = threadIdx.x;
  int wave = tid>>6, lane = tid&63, l15 = lane&15, l4 = lane>>4;
  int m0 = blockIdx.y*128, n0 = blockIdx.x*128;
  int wr = wave>>1, wc = wave&1;
  f32x4 acc[4][4];
  #pragma unroll
  for(int i=0;i<4;++i)
    #pragma unroll
    for(int j=0;j<4;++j) acc[i][j] = (f32x4){0.f,0.f,0.f,0.f};

  int c0r = tid,      row0 = c0r>>2, col0 = (c0r&3)*8;
  int c1r = tid+256,  row1 = c1r>>2, col1 = (c1r&3)*8;
  const unsigned short* a0p = A  + (size_t)(m0+row0)*1024 + col0;
  const unsigned short* a1p = A  + (size_t)(m0+row1)*1024 + col1;
  const unsigned short* b0p = Bt + (size_t)(n0+row0)*1024 + col0;
  const unsigned short* b1p = Bt + (size_t)(n0+row1)*1024 + col1;

  for(int k0=0; k0<1024; k0+=32){
    gload16(a0p + k0, &As[c0r*8]);
    gload16(a1p + k0, &As[c1r*8]);
    gload16(b0p + k0, &Bs[c0r*8]);
    gload16(b1p + k0, &Bs[c1r*8]);
    __syncthreads();
    bf16x8 af[4], bfr[4];
    #pragma unroll
    for(int t=0;t<4;++t){
      af[t]  = ld_bf8(&As[(wr*64 + t*16 + l15)*32 + 8*l4]);
      bfr[t] = ld_bf8(&Bs[(wc*64 + t*16 + l15)*32 + 8*l4]);
    }
    #pragma unroll
    for(int mt=0;mt<4;++mt)
      #pragma unroll
      for(int nt=0;nt<4;++nt)
        acc[mt][nt] = mfma16(af[mt], bfr[nt], acc[mt][nt]);
    __syncthreads();
  }

  #pragma unroll
  for(int mt=0;mt<4;++mt){
    #pragma unroll
    for(int nt=0;nt<4;++nt){
      int col = n0 + wc*64 + nt*16 + l15;
      float bb;
      if(col < 1024)      bb = g.bq[z][col];
      else if(col < 1536) bb = g.bk[z][col-1024];
      else                bb = g.bv[z][col-1536];
      #pragma unroll
      for(int r=0;r<4;++r){
        int row = m0 + wr*64 + mt*16 + l4*4 + r;
        C[(size_t)row*2048 + col] = f2bf(acc[mt][nt][r] + bb);
      }
    }
  }
}

// ---------------- V transpose: V[4096][512] (stride 2048) -> VT[512][4096] ----------------
struct VtArgs { const unsigned short* in[3]; unsigned short* out[3]; };
__global__ __launch_bounds__(256) void vtrans(VtArgs a){
  int z = blockIdx.z;
  const unsigned short* in = a.in[z];
  unsigned short* out = a.out[z];
  __shared__ unsigned short T[64][72];
  int r0 = blockIdx.x*64, c0 = blockIdx.y*64;
  int tid = threadIdx.x;
  #pragma unroll
  for(int p=0;p<4;++p){
    int e = p*1024 + tid*4;
    int row = e>>6, col = e&63;
    *(ushort4*)&T[row][col] = *(const ushort4*)&in[(size_t)(r0+row)*2048 + c0+col];
  }
  __syncthreads();
  #pragma unroll
  for(int p=0;p<4;++p){
    int e = p*1024 + tid*4;
    int orow = e>>6, ocol = e&63;
    ushort4 v = {T[ocol][orow], T[ocol+1][orow], T[ocol+2][orow], T[ocol+3][orow]};
    *(ushort4*)&out[(size_t)(c0+orow)*4096 + r0+ocol] = v;
  }
}

// ---------------- fused attention: 3 branches, one launch ----------------
// 12288 blocks x 256 threads (4 waves), 32KB LDS, NO XCD swizzle (r13 win).
// probs/ctx stores are NONTEMPORAL: write-once streams bypass L2 (avoid
// write-allocate pollution against the K/V/Q read stream).
// S layout: XOR-swizzled fp32 [16][512]: phys = row*512 + (((col>>2)^(row&7))<<2 | (col&3))
struct AttnArgs {
  const unsigned short* Q[3];  const unsigned short* Ka[3]; const unsigned short* Kb[3];
  const unsigned short* VTa[3]; const unsigned short* VTb[3];
  const float* mA[3]; const float* mB[3];
  float* ctx[3]; float* probs[3];
};
__global__ __launch_bounds__(256) void attn(AttnArgs A){
  __shared__ float S[16*512];                 // 32 KB
  int id = blockIdx.x;                        // sequential mapping (no swizzle)
  int br = id >> 12;
  int rem = id & 4095;
  int bh = rem >> 5, qt = rem & 31;
  int b = bh >> 4, h = bh & 15;
  const unsigned short* Q   = A.Q[br];
  const unsigned short* Ka  = A.Ka[br];
  const unsigned short* Kb  = A.Kb[br];
  const unsigned short* VTa = A.VTa[br];
  const unsigned short* VTb = A.VTb[br];
  const float* mA = A.mA[br];
  const float* mB = A.mB[br];
  float* ctx   = A.ctx[br];
  float* probs = A.probs[br];

  int tid = threadIdx.x, wave = tid>>6, lane = tid&63, l15 = lane&15, l4 = lane>>4;
  int q0 = qt*16;

  // ---- masks first (latency hides under everything else); float4, summed ----
  f32x4 msk4[2] = {{0.f,0.f,0.f,0.f},{0.f,0.f,0.f,0.f}};
  #pragma unroll
  for(int it=0; it<2; ++it){
    int c = it*256 + lane*4;
    if(mA) msk4[it] += *(const f32x4*)&mA[b*512 + c];
    if(mB) msk4[it] += *(const f32x4*)&mB[b*512 + c];
  }

  // ---- QK^T: batch-load all 16 K fragments, then MFMA chain ----
  const unsigned short* qp = Q + (size_t)(b*512 + q0 + l15)*2048 + h*64 + 8*l4;
  bf16x8 a0 = ld_bf8(qp);
  bf16x8 a1 = ld_bf8(qp + 32);
  int ct0 = wave*8;
  const unsigned short* kap = Ka + (size_t)(b*512 + ct0*16 + l15)*2048 + h*32 + 8*l4;
  const unsigned short* kbp = Kb + (size_t)(b*512 + ct0*16 + l15)*2048 + h*32 + 8*l4;
  bf16x8 ka[8], kb[8];
  #pragma unroll
  for(int t=0;t<8;++t){
    ka[t] = ld_bf8(kap + (size_t)t*16*2048);
    kb[t] = ld_bf8(kbp + (size_t)t*16*2048);
  }

  // ---- V prefetch issued while QK^T computes (T14) ----
  int d0 = wave*16 + l15;
  const unsigned short* vb0 = (d0<32 ? VTa + (size_t)(h*32+d0)*4096 : VTb + (size_t)(h*32+d0-32)*4096) + b*512;
  bf16x8 vpre[8];
  #pragma unroll
  for(int kc=0;kc<8;++kc) vpre[kc] = ld_bf8(vb0 + kc*32 + 8*l4);

  #pragma unroll
  for(int t=0;t<8;++t){
    int ct = ct0 + t;
    f32x4 acc = (f32x4){0.f,0.f,0.f,0.f};
    acc = mfma16(a0, ka[t], acc);
    acc = mfma16(a1, kb[t], acc);
    #pragma unroll
    for(int r=0;r<4;++r){
      int row = l4*4 + r;
      int col = ct*16 + l15;
      S[row*512 + ((((col>>2) ^ (row&7)) << 2) | (col&3))] = acc[r];
    }
  }
  __syncthreads();

  // ---- softmax: wave handles 4 rows; float4 lane-owns-4-consecutive-cols ----
  for(int rr=0; rr<4; ++rr){
    int r = wave*4 + rr;
    float* rowp = &S[r*512];
    int x = r & 7;
    f32x4 v[2];
    float m = -1e30f;
    #pragma unroll
    for(int it=0; it<2; ++it){
      int c4 = it*64 + lane;
      v[it] = *(const f32x4*)&rowp[(c4 ^ x) << 2];
      v[it] = v[it]*ATT_SCALE + msk4[it];
      m = fmaxf(m, fmaxf(fmaxf(v[it][0], v[it][1]), fmaxf(v[it][2], v[it][3])));
    }
    #pragma unroll
    for(int o=32;o;o>>=1) m = fmaxf(m, __shfl_xor(m, o));
    float sum = 0.f;
    #pragma unroll
    for(int it=0; it<2; ++it){
      #pragma unroll
      for(int j=0;j<4;++j){
        v[it][j] = __expf(v[it][j]-m);
        sum += v[it][j];
      }
    }
    #pragma unroll
    for(int o=32;o;o>>=1) sum += __shfl_xor(sum, o);
    float inv = 1.0f/sum;
    float* po = probs + ((size_t)bh*512 + (q0+r))*512;
    #pragma unroll
    for(int it=0; it<2; ++it){
      int c4 = it*64 + lane;
      f32x4 p = v[it]*inv;
      *(f32x4*)&rowp[(c4 ^ x) << 2] = p;
      __builtin_nontemporal_store(p, (f32x4*)&po[it*256 + lane*4]);   // nt stream
    }
  }
  __syncthreads();

  // ---- PV: wave = one 16-col d-tile, 16 rows ----
  int px = l15 & 7;
  const float* prowp = &S[l15*512];
  f32x4 accE = (f32x4){0.f,0.f,0.f,0.f}, accO = (f32x4){0.f,0.f,0.f,0.f};
  #pragma unroll
  for(int kc=0;kc<16;++kc){
    int c4a = kc*8 + 2*l4;
    float4 v0 = *(const float4*)&prowp[(c4a ^ px) << 2];
    float4 v1 = *(const float4*)&prowp[((c4a+1) ^ px) << 2];
    bf16x8 a = { (__bf16)v0.x,(__bf16)v0.y,(__bf16)v0.z,(__bf16)v0.w,
                 (__bf16)v1.x,(__bf16)v1.y,(__bf16)v1.z,(__bf16)v1.w };
    bf16x8 bb = (kc < 8) ? vpre[kc] : ld_bf8(vb0 + kc*32 + 8*l4);
    if(kc & 1) accO = mfma16(a, bb, accO);
    else       accE = mfma16(a, bb, accE);
  }
  f32x4 acc = accE + accO;
  #pragma unroll
  for(int r=0;r<4;++r){
    int row = q0 + l4*4 + r;
    __builtin_nontemporal_store(acc[r], &ctx[((size_t)(b*512+row))*1024 + h*64 + d0]);
  }
}

// ---------------- launch ----------------
extern "C" void kernel_launch(void* const* d_in, const int* in_sizes, int n_in,
                              void* d_out, int out_size, void* d_ws, size_t ws_size,
                              hipStream_t stream){
  const float* x[3]    = {(const float*)d_in[0], (const float*)d_in[2], (const float*)d_in[4]};
  const float* mask[3] = {(const float*)d_in[1], (const float*)d_in[3], (const float*)d_in[5]};
  const float *wq[3], *bq[3], *wk[3], *bk[3], *wv[3], *bv[3];
  for(int i=0;i<3;++i){
    wq[i]=(const float*)d_in[6+6*i];  bq[i]=(const float*)d_in[7+6*i];
    wk[i]=(const float*)d_in[8+6*i];  bk[i]=(const float*)d_in[9+6*i];
    wv[i]=(const float*)d_in[10+6*i]; bv[i]=(const float*)d_in[11+6*i];
  }

  unsigned short* ws = (unsigned short*)d_ws;
  unsigned short *Xb[3], *WT[3], *QKV[3], *VT[3];
  for(int i=0;i<3;++i){
    Xb[i]  = ws + (size_t)i*4194304;            // 4096x1024 bf16 (dead after gemm)
    VT[i]  = Xb[i];                             // 512x4096 bf16, aliases Xb
    WT[i]  = ws + 12582912 + (size_t)i*2097152; // 2048x1024 bf16 packed [Wq;Wk;Wv]^T
    QKV[i] = ws + 18874368 + (size_t)i*8388608; // 4096x2048 bf16
  }

  CastArgs ca;
  for(int i=0;i<3;++i){ ca.src[i]=x[i]; ca.dst[i]=Xb[i]; }
  cast_f32_bf16<<<dim3(4096,3), 256, 0, stream>>>(ca);

  WtArgs wa;
  for(int i=0;i<3;++i){
    wa.src[3*i+0]=wq[i]; wa.dst[3*i+0]=WT[i];           wa.N[3*i+0]=1024;
    wa.src[3*i+1]=wk[i]; wa.dst[3*i+1]=WT[i]+1048576;   wa.N[3*i+1]=512;
    wa.src[3*i+2]=wv[i]; wa.dst[3*i+2]=WT[i]+1572864;   wa.N[3*i+2]=512;
  }
  wtrans<<<dim3(32,32,9), dim3(32,8), 0, stream>>>(wa);

  GemmArgs ga;
  for(int i=0;i<3;++i){
    ga.X[i]=Xb[i]; ga.WT[i]=WT[i]; ga.bq[i]=bq[i]; ga.bk[i]=bk[i]; ga.bv[i]=bv[i]; ga.C[i]=QKV[i];
  }
  gemm_qkv<<<dim3(16,32,3), 256, 0, stream>>>(ga);

  VtArgs va;
  for(int i=0;i<3;++i){ va.in[i]=QKV[i]+1536; va.out[i]=VT[i]; }
  vtrans<<<dim3(64,8,3), 256, 0, stream>>>(va);

  float* out = (float*)d_out;
  float* ctx2 = out;
  float* ctx1 = out + 4194304;
  float* ctx3 = out + 8388608;
  float* p2   = out + 12582912;
  float* p1   = out + 46137344;
  float* p3   = out + 79691776;

  AttnArgs aa;
  // br0 = "c2": q1, KV 2+3, no mask
  aa.Q[0]=QKV[0]; aa.Ka[0]=QKV[1]+1024; aa.Kb[0]=QKV[2]+1024; aa.VTa[0]=VT[1]; aa.VTb[0]=VT[2];
  aa.mA[0]=nullptr; aa.mB[0]=nullptr; aa.ctx[0]=ctx2; aa.probs[0]=p2;
  // br1 = "c1": q2, KV 1+3, mask1+mask3
  aa.Q[1]=QKV[1]; aa.Ka[1]=QKV[0]+1024; aa.Kb[1]=QKV[2]+1024; aa.VTa[1]=VT[0]; aa.VTb[1]=VT[2];
  aa.mA[1]=mask[0]; aa.mB[1]=mask[2]; aa.ctx[1]=ctx1; aa.probs[1]=p1;
  // br2 = "c3": q3, KV 1+2, mask1+mask2
  aa.Q[2]=QKV[2]; aa.Ka[2]=QKV[0]+1024; aa.Kb[2]=QKV[1]+1024; aa.VTa[2]=VT[0]; aa.VTb[2]=VT[1];
  aa.mA[2]=mask[0]; aa.mB[2]=mask[1]; aa.ctx[2]=ctx3; aa.probs[2]=p3;
  attn<<<12288, 256, 0, stream>>>(aa);
}